// Round 1
// baseline (361.431 us; speedup 1.0000x reference)
//
#include <hip/hip_runtime.h>
#include <math.h>

#define DDIM 512
#define THREADS 256
#define BM 64
#define BN 64
#define BK 64
#define PAD 68          // BM + 4: keeps float4 alignment AND breaks staging bank conflicts
#define NCHUNK 16       // column chunks -> grid 64x16 = 1024 blocks = 4 blocks/CU

// ---------------- kernel 1: row-normalize z = [z_i; z_j] -> zn ----------------
__global__ void k_normalize(const float* __restrict__ zi,
                            const float* __restrict__ zj,
                            float* __restrict__ zn, int B) {
  int gw = (blockIdx.x * blockDim.x + threadIdx.x) >> 6;  // one wave per row
  int lane = threadIdx.x & 63;
  int N = 2 * B;
  if (gw >= N) return;
  const float* src = (gw < B) ? (zi + (size_t)gw * DDIM)
                              : (zj + (size_t)(gw - B) * DDIM);
  float v[8];
  float ss = 0.f;
#pragma unroll
  for (int i = 0; i < 8; ++i) { v[i] = src[lane + 64 * i]; ss += v[i] * v[i]; }
#pragma unroll
  for (int off = 32; off; off >>= 1) ss += __shfl_xor(ss, off, 64);
  float inv = 1.f / fmaxf(sqrtf(ss), 1e-8f);
  float* dst = zn + (size_t)gw * DDIM;
#pragma unroll
  for (int i = 0; i < 8; ++i) dst[lane + 64 * i] = v[i] * inv;
}

// ---------------- kernel 2: pos[r] = dot(zn[r], zn[partner(r)]) / temp --------
__global__ void k_pos(const float* __restrict__ zn, float* __restrict__ pos,
                      const float* __restrict__ tempp, int B) {
  int gw = (blockIdx.x * blockDim.x + threadIdx.x) >> 6;
  int lane = threadIdx.x & 63;
  int N = 2 * B;
  if (gw >= N) return;
  int p = (gw < B) ? gw + B : gw - B;
  const float* a = zn + (size_t)gw * DDIM;
  const float* b = zn + (size_t)p * DDIM;
  float acc = 0.f;
#pragma unroll
  for (int i = 0; i < 8; ++i) acc = fmaf(a[lane + 64 * i], b[lane + 64 * i], acc);
#pragma unroll
  for (int off = 32; off; off >>= 1) acc += __shfl_xor(acc, off, 64);
  if (lane == 0) pos[gw] = acc / tempp[0];
}

// ---------------- kernel 3: fused tiled zn*zn^T with online LSE + rank count --
__global__ __launch_bounds__(THREADS) void k_main(
    const float* __restrict__ zn, const float* __restrict__ pos,
    const float* __restrict__ tempp, float* __restrict__ partM,
    float* __restrict__ partS, float* __restrict__ partC, int B) {
  const int N = 2 * B;
  const int r0 = blockIdx.x * BM;
  const int chunk = blockIdx.y;
  const int chunk_cols = N / NCHUNK;           // 256
  const int c0chunk = chunk * chunk_cols;
  const float invt = 1.0f / tempp[0];

  __shared__ float As[BK][PAD];                // [k][row], transposed stage
  __shared__ float Bs[BK][PAD];                // [k][col]

  const int t = threadIdx.x;
  const int ty = t >> 4;                       // 0..15: rows ty*4..ty*4+3
  const int tx = t & 15;                       // 0..15: cols tx*4..tx*4+3
  const int skq = t & 15;                      // staging: float4 index along k
  const int srow = t >> 4;                     // staging: base row (+16*i)

  float m[4], s[4], cnt[4], posv[4];
  int grow[4], part[4];
#pragma unroll
  for (int i = 0; i < 4; ++i) {
    m[i] = -INFINITY; s[i] = 0.f; cnt[i] = 0.f;
    grow[i] = r0 + ty * 4 + i;
    part[i] = (grow[i] < B) ? grow[i] + B : grow[i] - B;
    posv[i] = pos[grow[i]];
  }

  for (int ct = 0; ct < chunk_cols / BN; ++ct) {  // 4 col tiles per chunk
    const int c0 = c0chunk + ct * BN;
    float acc[4][4];
#pragma unroll
    for (int i = 0; i < 4; ++i)
#pragma unroll
      for (int j = 0; j < 4; ++j) acc[i][j] = 0.f;

    for (int kt = 0; kt < DDIM / BK; ++kt) {      // 8 k tiles
      const int k0 = kt * BK;
#pragma unroll
      for (int i = 0; i < 4; ++i) {
        int rr = srow + 16 * i;
        float4 v = *(const float4*)(zn + (size_t)(r0 + rr) * DDIM + k0 + skq * 4);
        As[skq * 4 + 0][rr] = v.x; As[skq * 4 + 1][rr] = v.y;
        As[skq * 4 + 2][rr] = v.z; As[skq * 4 + 3][rr] = v.w;
        float4 w = *(const float4*)(zn + (size_t)(c0 + rr) * DDIM + k0 + skq * 4);
        Bs[skq * 4 + 0][rr] = w.x; Bs[skq * 4 + 1][rr] = w.y;
        Bs[skq * 4 + 2][rr] = w.z; Bs[skq * 4 + 3][rr] = w.w;
      }
      __syncthreads();
#pragma unroll
      for (int k = 0; k < BK; ++k) {
        float4 av = *(const float4*)&As[k][ty * 4];
        float4 bv = *(const float4*)&Bs[k][tx * 4];
        float a4[4] = {av.x, av.y, av.z, av.w};
        float b4[4] = {bv.x, bv.y, bv.z, bv.w};
#pragma unroll
        for (int i = 0; i < 4; ++i)
#pragma unroll
          for (int j = 0; j < 4; ++j) acc[i][j] = fmaf(a4[i], b4[j], acc[i][j]);
      }
      __syncthreads();
    }

    // epilogue: online max/sum + rank count for this 64x64 tile
#pragma unroll
    for (int i = 0; i < 4; ++i) {
      float v[4];
      float rmax = -INFINITY;
#pragma unroll
      for (int j = 0; j < 4; ++j) {
        int c = c0 + tx * 4 + j;
        float val = acc[i][j] * invt;
        cnt[i] += (c != grow[i] && c != part[i] && val > posv[i]) ? 1.f : 0.f;
        if (c == grow[i]) val = -INFINITY;     // exclude diagonal from LSE
        v[j] = val;
        rmax = fmaxf(rmax, val);
      }
#pragma unroll
      for (int off = 1; off < 16; off <<= 1)
        rmax = fmaxf(rmax, __shfl_xor(rmax, off, 64));
      float newm = fmaxf(m[i], rmax);          // finite after reduce
      float scale = __expf(m[i] - newm);       // exp(-inf)=0 on first tile
      float add = __expf(v[0] - newm) + __expf(v[1] - newm) +
                  __expf(v[2] - newm) + __expf(v[3] - newm);
      s[i] = s[i] * scale + add;
      m[i] = newm;
    }
  }

  // per-row partials for this chunk
#pragma unroll
  for (int i = 0; i < 4; ++i) {
    float sv = s[i], cv = cnt[i];
#pragma unroll
    for (int off = 1; off < 16; off <<= 1) {
      sv += __shfl_xor(sv, off, 64);
      cv += __shfl_xor(cv, off, 64);
    }
    if (tx == 0) {
      partM[(size_t)grow[i] * NCHUNK + chunk] = m[i];
      partS[(size_t)grow[i] * NCHUNK + chunk] = sv;
      partC[(size_t)grow[i] * NCHUNK + chunk] = cv;
    }
  }
}

// ---------------- kernel 4: combine chunks, reduce to (loss, avg_rank) -------
__global__ void k_finalize(const float* __restrict__ partM,
                           const float* __restrict__ partS,
                           const float* __restrict__ partC,
                           const float* __restrict__ pos,
                           float* __restrict__ out, int B) {
  const int N = 2 * B;
  float lsum = 0.f, csum = 0.f;
  for (int r = threadIdx.x; r < N; r += THREADS) {
    float mm = -INFINITY;
#pragma unroll
    for (int k = 0; k < NCHUNK; ++k)
      mm = fmaxf(mm, partM[(size_t)r * NCHUNK + k]);
    float ss = 0.f, cc = 0.f;
#pragma unroll
    for (int k = 0; k < NCHUNK; ++k) {
      ss += partS[(size_t)r * NCHUNK + k] * expf(partM[(size_t)r * NCHUNK + k] - mm);
      cc += partC[(size_t)r * NCHUNK + k];
    }
    lsum += (mm + logf(ss)) - pos[r];
    csum += cc;
  }
  __shared__ float ls[THREADS], cs[THREADS];
  ls[threadIdx.x] = lsum; cs[threadIdx.x] = csum;
  __syncthreads();
  for (int off = THREADS / 2; off; off >>= 1) {
    if (threadIdx.x < off) {
      ls[threadIdx.x] += ls[threadIdx.x + off];
      cs[threadIdx.x] += cs[threadIdx.x + off];
    }
    __syncthreads();
  }
  if (threadIdx.x == 0) {
    out[0] = ls[0] / (float)N;
    out[1] = cs[0] / (float)N;
  }
}

extern "C" void kernel_launch(void* const* d_in, const int* in_sizes, int n_in,
                              void* d_out, int out_size, void* d_ws, size_t ws_size,
                              hipStream_t stream) {
  const float* zi = (const float*)d_in[0];
  const float* zj = (const float*)d_in[1];
  const float* temp = (const float*)d_in[2];
  float* out = (float*)d_out;

  const int B = in_sizes[0] / DDIM;   // 2048
  const int N = 2 * B;                // 4096

  float* ws = (float*)d_ws;
  float* zn  = ws;                               // N*DDIM
  float* pos = zn + (size_t)N * DDIM;            // N
  float* pM  = pos + N;                          // N*NCHUNK
  float* pS  = pM + (size_t)N * NCHUNK;          // N*NCHUNK
  float* pC  = pS + (size_t)N * NCHUNK;          // N*NCHUNK

  int waves_blocks = (N * 64) / THREADS;         // 1024
  k_normalize<<<waves_blocks, THREADS, 0, stream>>>(zi, zj, zn, B);
  k_pos<<<waves_blocks, THREADS, 0, stream>>>(zn, pos, temp, B);
  dim3 grid(N / BM, NCHUNK);                     // 64 x 16
  k_main<<<grid, THREADS, 0, stream>>>(zn, pos, temp, pM, pS, pC, B);
  k_finalize<<<1, THREADS, 0, stream>>>(pM, pS, pC, pos, out, B);
}

// Round 2
// 53.455 us; speedup vs baseline: 6.7614x; 6.7614x over previous
//
#include <hip/hip_runtime.h>
#include <math.h>

#define DDIM 512
#define THREADS 256
#define BT 128          // block tile (M and N)
#define BK 64           // K-step (one staged LDS tile)
#define NCH 64          // column chunks of 64 (one per wave-column) for partials

typedef __attribute__((ext_vector_type(8))) __bf16 bf16x8;
typedef __attribute__((ext_vector_type(4))) float f32x4;
typedef __attribute__((ext_vector_type(8))) unsigned short ushort8;

__device__ __forceinline__ float bf2f(unsigned short u) {
  union { unsigned int i; float f; } v; v.i = ((unsigned int)u) << 16; return v.f;
}
__device__ __forceinline__ unsigned short f2bf(float f) {
  unsigned int u = __builtin_bit_cast(unsigned int, f);
  return (unsigned short)((u + 0x7fffu + ((u >> 16) & 1u)) >> 16);
}

#define GLOAD_LDS16(gp, lp)                                                   \
  __builtin_amdgcn_global_load_lds(                                           \
      (const __attribute__((address_space(1))) unsigned int*)(gp),            \
      (__attribute__((address_space(3))) unsigned int*)(lp), 16, 0, 0)

// ---- kernel 1: normalize rows w and w+B to bf16, compute pos[w]=dot/temp ----
__global__ void k_prep(const float* __restrict__ zi, const float* __restrict__ zj,
                       const float* __restrict__ tempp,
                       unsigned short* __restrict__ znb, float* __restrict__ pos,
                       int B) {
  int wv = (blockIdx.x * blockDim.x + threadIdx.x) >> 6;
  int lane = threadIdx.x & 63;
  if (wv >= B) return;
  const float* a = zi + (size_t)wv * DDIM;
  const float* b = zj + (size_t)wv * DDIM;
  float4 a0 = *(const float4*)(a + lane * 8);
  float4 a1 = *(const float4*)(a + lane * 8 + 4);
  float4 b0 = *(const float4*)(b + lane * 8);
  float4 b1 = *(const float4*)(b + lane * 8 + 4);
  float av[8] = {a0.x, a0.y, a0.z, a0.w, a1.x, a1.y, a1.z, a1.w};
  float bv[8] = {b0.x, b0.y, b0.z, b0.w, b1.x, b1.y, b1.z, b1.w};
  float sa = 0.f, sb = 0.f;
#pragma unroll
  for (int i = 0; i < 8; ++i) { sa = fmaf(av[i], av[i], sa); sb = fmaf(bv[i], bv[i], sb); }
#pragma unroll
  for (int off = 32; off; off >>= 1) { sa += __shfl_xor(sa, off, 64); sb += __shfl_xor(sb, off, 64); }
  float ia = 1.f / fmaxf(sqrtf(sa), 1e-8f);
  float ib = 1.f / fmaxf(sqrtf(sb), 1e-8f);
  ushort8 ua, ub;
  float fa[8], fb[8];
#pragma unroll
  for (int i = 0; i < 8; ++i) {
    unsigned short x = f2bf(av[i] * ia); ua[i] = x; fa[i] = bf2f(x);
    unsigned short y = f2bf(bv[i] * ib); ub[i] = y; fb[i] = bf2f(y);
  }
  *(ushort8*)(znb + (size_t)wv * DDIM + lane * 8) = ua;
  *(ushort8*)(znb + (size_t)(wv + B) * DDIM + lane * 8) = ub;
  float pd = 0.f;
#pragma unroll
  for (int i = 0; i < 8; ++i) pd = fmaf(fa[i], fb[i], pd);
#pragma unroll
  for (int off = 32; off; off >>= 1) pd += __shfl_xor(pd, off, 64);
  if (lane == 0) {
    float p = pd / tempp[0];
    pos[wv] = p; pos[wv + B] = p;
  }
}

// ---- kernel 2: MFMA Gram-matrix tile + fused sum-exp / rank-count epilogue ----
__global__ __launch_bounds__(THREADS) void k_main(
    const unsigned short* __restrict__ znb, const float* __restrict__ pos,
    const float* __restrict__ tempp, float* __restrict__ partS,
    float* __restrict__ partC, int B) {
  const int r0 = blockIdx.x * BT;
  const int c0 = blockIdx.y * BT;
  const float invt = 1.0f / tempp[0];

  __shared__ __align__(16) unsigned char sA[BT * BK * 2];  // 16 KB, [row][slot] 16B units
  __shared__ __align__(16) unsigned char sB[BT * BK * 2];  // 16 KB

  const int t = threadIdx.x;
  const int lane = t & 63;
  const int wave = t >> 6;
  const int wr = wave >> 1, wc = wave & 1;   // 2x2 wave grid, each 64x64
  const int cl = lane & 15, g = lane >> 4;

  // staging source offsets (pre-swizzled global address; LDS stays linear)
  const int srow_in = lane >> 3;                       // 0..7 within region
  const int sphys = lane & 7;                          // physical 16B slot
  const int slog = sphys ^ srow_in;                    // logical k-slot (involution)

  f32x4 acc[4][4];
#pragma unroll
  for (int m = 0; m < 4; ++m)
#pragma unroll
    for (int n = 0; n < 4; ++n) acc[m][n] = (f32x4){0.f, 0.f, 0.f, 0.f};

  for (int kt = 0; kt < DDIM / BK; ++kt) {   // 8 K-tiles
    const int k0 = kt * BK;
#pragma unroll
    for (int j = 0; j < 4; ++j) {
      const int ww = wave * 4 + j;           // region 0..15 (8 rows of 128B)
      const int row = 8 * ww + srow_in;
      const unsigned short* gA = znb + (size_t)(r0 + row) * DDIM + k0 + slog * 8;
      const unsigned short* gB = znb + (size_t)(c0 + row) * DDIM + k0 + slog * 8;
      GLOAD_LDS16(gA, sA + ww * 1024);
      GLOAD_LDS16(gB, sB + ww * 1024);
    }
    __syncthreads();   // compiler drains vmcnt before barrier -> LDS ready

#pragma unroll
    for (int ks = 0; ks < 2; ++ks) {
      const int phys = (g + ks * 4) ^ (cl & 7);        // same for all m (row&7 == cl&7)
      bf16x8 aF[4], bF[4];
#pragma unroll
      for (int m = 0; m < 4; ++m) {
        int arow = wr * 64 + m * 16 + cl;
        aF[m] = *(const bf16x8*)(sA + arow * 128 + phys * 16);
      }
#pragma unroll
      for (int n = 0; n < 4; ++n) {
        int brow = wc * 64 + n * 16 + cl;
        bF[n] = *(const bf16x8*)(sB + brow * 128 + phys * 16);
      }
#pragma unroll
      for (int m = 0; m < 4; ++m)
#pragma unroll
        for (int n = 0; n < 4; ++n)
          acc[m][n] = __builtin_amdgcn_mfma_f32_16x16x32_bf16(aF[m], bF[n], acc[m][n], 0, 0, 0);
    }
    __syncthreads();
  }

  // epilogue: per-row sum(exp) excluding diagonal, count(> pos) excluding diag+partner
  const int chunkc = blockIdx.y * 2 + wc;   // 64-wide column chunk id
#pragma unroll
  for (int m = 0; m < 4; ++m) {
#pragma unroll
    for (int reg = 0; reg < 4; ++reg) {
      int grow = r0 + wr * 64 + m * 16 + g * 4 + reg;
      int gpart = (grow < B) ? grow + B : grow - B;
      float pv = pos[grow];
      float ss = 0.f, cc = 0.f;
#pragma unroll
      for (int n = 0; n < 4; ++n) {
        int gcol = c0 + wc * 64 + n * 16 + cl;
        float val = acc[m][n][reg] * invt;
        if (gcol != grow) {
          ss += __expf(val);
          cc += (gcol != gpart && val > pv) ? 1.f : 0.f;
        }
      }
#pragma unroll
      for (int off = 1; off < 16; off <<= 1) {
        ss += __shfl_xor(ss, off, 64);
        cc += __shfl_xor(cc, off, 64);
      }
      if (cl == 0) {
        partS[(size_t)grow * NCH + chunkc] = ss;
        partC[(size_t)grow * NCH + chunkc] = cc;
      }
    }
  }
}

// ---- kernel 3: per-row combine of 64 chunks -> rowLoss, rowCnt ----
__global__ void k_rowfin(const float* __restrict__ partS, const float* __restrict__ partC,
                         const float* __restrict__ pos, float* __restrict__ rowL,
                         float* __restrict__ rowC, int N) {
  int r = (blockIdx.x * blockDim.x + threadIdx.x) >> 6;
  int lane = threadIdx.x & 63;
  if (r >= N) return;
  float s = partS[(size_t)r * NCH + lane];
  float c = partC[(size_t)r * NCH + lane];
#pragma unroll
  for (int off = 32; off; off >>= 1) { s += __shfl_xor(s, off, 64); c += __shfl_xor(c, off, 64); }
  if (lane == 0) {
    rowL[r] = logf(s) - pos[r];
    rowC[r] = c;
  }
}

// ---- kernel 4: final reduction to (loss, avg_rank) ----
__global__ void k_final(const float* __restrict__ rowL, const float* __restrict__ rowC,
                        float* __restrict__ out, int N) {
  float ls = 0.f, cs = 0.f;
  for (int r = threadIdx.x; r < N; r += THREADS) { ls += rowL[r]; cs += rowC[r]; }
  __shared__ float l[THREADS], c[THREADS];
  l[threadIdx.x] = ls; c[threadIdx.x] = cs;
  __syncthreads();
  for (int off = THREADS / 2; off; off >>= 1) {
    if (threadIdx.x < off) { l[threadIdx.x] += l[threadIdx.x + off]; c[threadIdx.x] += c[threadIdx.x + off]; }
    __syncthreads();
  }
  if (threadIdx.x == 0) { out[0] = l[0] / (float)N; out[1] = c[0] / (float)N; }
}

extern "C" void kernel_launch(void* const* d_in, const int* in_sizes, int n_in,
                              void* d_out, int out_size, void* d_ws, size_t ws_size,
                              hipStream_t stream) {
  const float* zi = (const float*)d_in[0];
  const float* zj = (const float*)d_in[1];
  const float* temp = (const float*)d_in[2];
  float* out = (float*)d_out;

  const int B = in_sizes[0] / DDIM;   // 2048
  const int N = 2 * B;                // 4096

  unsigned short* znb = (unsigned short*)d_ws;          // N*DDIM bf16 = 4 MB
  float* fws = (float*)(znb + (size_t)N * DDIM);
  float* pos   = fws;                                    // N
  float* partS = pos + N;                                // N*NCH = 1 MB
  float* partC = partS + (size_t)N * NCH;                // N*NCH = 1 MB
  float* rowL  = partC + (size_t)N * NCH;                // N
  float* rowC  = rowL + N;                               // N

  k_prep<<<(B * 64) / THREADS, THREADS, 0, stream>>>(zi, zj, temp, znb, pos, B);
  dim3 grid(N / BT, N / BT);                             // 32 x 32
  k_main<<<grid, THREADS, 0, stream>>>(znb, pos, temp, partS, partC, B);
  k_rowfin<<<(N * 64) / THREADS, THREADS, 0, stream>>>(partS, partC, pos, rowL, rowC, N);
  k_final<<<1, THREADS, 0, stream>>>(rowL, rowC, out, N);
}

// Round 3
// 50.889 us; speedup vs baseline: 7.1023x; 1.0504x over previous
//
#include <hip/hip_runtime.h>
#include <math.h>

#define DDIM 512
#define THREADS 256
#define BT 128          // block tile (M and N)
#define BK 64           // K-step (one staged LDS tile)
#define NT 32           // N / BT tile grid dimension
#define NCH 64          // 64-wide column chunks for partials

typedef __attribute__((ext_vector_type(8))) __bf16 bf16x8;
typedef __attribute__((ext_vector_type(4))) float f32x4;
typedef __attribute__((ext_vector_type(8))) unsigned short ushort8;

__device__ __forceinline__ float bf2f(unsigned short u) {
  union { unsigned int i; float f; } v; v.i = ((unsigned int)u) << 16; return v.f;
}
__device__ __forceinline__ unsigned short f2bf(float f) {
  unsigned int u = __builtin_bit_cast(unsigned int, f);
  return (unsigned short)((u + 0x7fffu + ((u >> 16) & 1u)) >> 16);
}

#define GLOAD_LDS16(gp, lp)                                                   \
  __builtin_amdgcn_global_load_lds(                                           \
      (const __attribute__((address_space(1))) unsigned int*)(gp),            \
      (__attribute__((address_space(3))) unsigned int*)(lp), 16, 0, 0)

// ---- kernel 1: normalize rows w and w+B to bf16, compute pos[w]=dot/temp ----
__global__ void k_prep(const float* __restrict__ zi, const float* __restrict__ zj,
                       const float* __restrict__ tempp,
                       unsigned short* __restrict__ znb, float* __restrict__ pos,
                       int B) {
  int wv = (blockIdx.x * blockDim.x + threadIdx.x) >> 6;
  int lane = threadIdx.x & 63;
  if (wv >= B) return;
  const float* a = zi + (size_t)wv * DDIM;
  const float* b = zj + (size_t)wv * DDIM;
  float4 a0 = *(const float4*)(a + lane * 8);
  float4 a1 = *(const float4*)(a + lane * 8 + 4);
  float4 b0 = *(const float4*)(b + lane * 8);
  float4 b1 = *(const float4*)(b + lane * 8 + 4);
  float av[8] = {a0.x, a0.y, a0.z, a0.w, a1.x, a1.y, a1.z, a1.w};
  float bv[8] = {b0.x, b0.y, b0.z, b0.w, b1.x, b1.y, b1.z, b1.w};
  float sa = 0.f, sb = 0.f;
#pragma unroll
  for (int i = 0; i < 8; ++i) { sa = fmaf(av[i], av[i], sa); sb = fmaf(bv[i], bv[i], sb); }
#pragma unroll
  for (int off = 32; off; off >>= 1) { sa += __shfl_xor(sa, off, 64); sb += __shfl_xor(sb, off, 64); }
  float ia = 1.f / fmaxf(sqrtf(sa), 1e-8f);
  float ib = 1.f / fmaxf(sqrtf(sb), 1e-8f);
  ushort8 ua, ub;
  float fa[8], fb[8];
#pragma unroll
  for (int i = 0; i < 8; ++i) {
    unsigned short x = f2bf(av[i] * ia); ua[i] = x; fa[i] = bf2f(x);
    unsigned short y = f2bf(bv[i] * ib); ub[i] = y; fb[i] = bf2f(y);
  }
  *(ushort8*)(znb + (size_t)wv * DDIM + lane * 8) = ua;
  *(ushort8*)(znb + (size_t)(wv + B) * DDIM + lane * 8) = ub;
  float pd = 0.f;
#pragma unroll
  for (int i = 0; i < 8; ++i) pd = fmaf(fa[i], fb[i], pd);
#pragma unroll
  for (int off = 32; off; off >>= 1) pd += __shfl_xor(pd, off, 64);
  if (lane == 0) {
    float p = pd / tempp[0];
    pos[wv] = p; pos[wv + B] = p;
  }
}

// stage one 128x64 bf16 panel into LDS (linear dest, swizzled global source)
__device__ __forceinline__ void stage_tile(const unsigned short* __restrict__ znb,
                                           int panel0, int k0, unsigned char* dst,
                                           int wave, int lane) {
  const int srow_in = lane >> 3;                  // 0..7 within 8-row region
  const int slog = (lane & 7) ^ srow_in;          // logical 16B k-slot (involution)
#pragma unroll
  for (int j = 0; j < 4; ++j) {
    const int ww = wave * 4 + j;                  // region 0..15
    const int row = 8 * ww + srow_in;
    GLOAD_LDS16(znb + (size_t)(panel0 + row) * DDIM + k0 + slog * 8, dst + ww * 1024);
  }
}

// ---- kernel 2: symmetric MFMA Gram tiles + dual-direction fused epilogue ----
__global__ __launch_bounds__(THREADS) void k_main(
    const unsigned short* __restrict__ znb, const float* __restrict__ pos,
    const float* __restrict__ tempp, float* __restrict__ partS,
    float* __restrict__ partC, int B) {
  // decode upper-triangular tile (bi <= bj)
  int l = blockIdx.x;
  int bi = 0;
  while (l >= NT - bi) { l -= NT - bi; ++bi; }
  const int bj = bi + l;
  const int r0 = bi * BT, c0 = bj * BT;
  const bool diag = (bi == bj);
  const float invt = 1.0f / tempp[0];

  __shared__ __align__(16) unsigned char sA[2][BT * BK * 2];  // 2 x 16 KB
  __shared__ __align__(16) unsigned char sB[2][BT * BK * 2];  // 2 x 16 KB

  const int t = threadIdx.x;
  const int lane = t & 63;
  const int wave = t >> 6;
  const int wr = wave >> 1, wc = wave & 1;   // 2x2 wave grid, each 64x64
  const int cl = lane & 15, g = lane >> 4;

  f32x4 acc[4][4];
#pragma unroll
  for (int m = 0; m < 4; ++m)
#pragma unroll
    for (int n = 0; n < 4; ++n) acc[m][n] = (f32x4){0.f, 0.f, 0.f, 0.f};

  // prologue: stage K-tile 0
  stage_tile(znb, r0, 0, sA[0], wave, lane);
  if (!diag) stage_tile(znb, c0, 0, sB[0], wave, lane);
  __syncthreads();

  for (int kt = 0; kt < DDIM / BK; ++kt) {   // 8 K-tiles, 2-phase dbuf
    const int cur = kt & 1;
    if (kt < DDIM / BK - 1) {                // issue next stage BEFORE compute
      stage_tile(znb, r0, (kt + 1) * BK, sA[cur ^ 1], wave, lane);
      if (!diag) stage_tile(znb, c0, (kt + 1) * BK, sB[cur ^ 1], wave, lane);
    }
    const unsigned char* pA = sA[cur];
    const unsigned char* pB = diag ? sA[cur] : sB[cur];
#pragma unroll
    for (int ks = 0; ks < 2; ++ks) {
      const int phys = (g + ks * 4) ^ (cl & 7);
      bf16x8 aF[4], bF[4];
#pragma unroll
      for (int m = 0; m < 4; ++m)
        aF[m] = *(const bf16x8*)(pA + (wr * 64 + m * 16 + cl) * 128 + phys * 16);
#pragma unroll
      for (int n = 0; n < 4; ++n)
        bF[n] = *(const bf16x8*)(pB + (wc * 64 + n * 16 + cl) * 128 + phys * 16);
#pragma unroll
      for (int m = 0; m < 4; ++m)
#pragma unroll
        for (int n = 0; n < 4; ++n)
          acc[m][n] = __builtin_amdgcn_mfma_f32_16x16x32_bf16(aF[m], bF[n], acc[m][n], 0, 0, 0);
    }
    __syncthreads();   // drains vmcnt (next stage) + lgkm, releases buffers
  }

  // ---- epilogue: row partials (always) + col partials (off-diag tiles) ----
  int growv[16], gpartr[16];
  float pvr[16];
#pragma unroll
  for (int m = 0; m < 4; ++m)
#pragma unroll
    for (int reg = 0; reg < 4; ++reg) {
      int idx = m * 4 + reg;
      int grow = r0 + wr * 64 + m * 16 + g * 4 + reg;
      growv[idx] = grow;
      gpartr[idx] = (grow < B) ? grow + B : grow - B;
      pvr[idx] = pos[grow];
    }
  int gcolv[4], gpartc[4];
  float pvc[4];
#pragma unroll
  for (int n = 0; n < 4; ++n) {
    int gcol = c0 + wc * 64 + n * 16 + cl;
    gcolv[n] = gcol;
    gpartc[n] = (gcol < B) ? gcol + B : gcol - B;
    pvc[n] = pos[gcol];
  }

  float ssr[16], ccr[16], ssc[4], ccc[4];
#pragma unroll
  for (int i = 0; i < 16; ++i) { ssr[i] = 0.f; ccr[i] = 0.f; }
#pragma unroll
  for (int n = 0; n < 4; ++n) { ssc[n] = 0.f; ccc[n] = 0.f; }

#pragma unroll
  for (int m = 0; m < 4; ++m)
#pragma unroll
    for (int n = 0; n < 4; ++n)
#pragma unroll
      for (int reg = 0; reg < 4; ++reg) {
        const int idx = m * 4 + reg;
        float val = acc[m][n][reg] * invt;
        float e = __expf(val);
        bool isd = diag && (gcolv[n] == growv[idx]);
        if (!isd) {
          ssr[idx] += e;
          ccr[idx] += (gcolv[n] != gpartr[idx] && val > pvr[idx]) ? 1.f : 0.f;
        }
        if (!diag) {
          ssc[n] += e;
          ccc[n] += (growv[idx] != gpartc[n] && val > pvc[n]) ? 1.f : 0.f;
        }
      }

  // row partials: reduce over cl (16 lanes), write chunk 2*bj + wc
  const int chR = bj * 2 + wc;
#pragma unroll
  for (int idx = 0; idx < 16; ++idx) {
    float s = ssr[idx], c = ccr[idx];
#pragma unroll
    for (int off = 1; off < 16; off <<= 1) {
      s += __shfl_xor(s, off, 64);
      c += __shfl_xor(c, off, 64);
    }
    if (cl == 0) {
      partS[(size_t)growv[idx] * NCH + chR] = s;
      partC[(size_t)growv[idx] * NCH + chR] = c;
    }
  }
  // col partials: reduce over g (xor 16,32), write chunk 2*bi + wr
  if (!diag) {
    const int chC = bi * 2 + wr;
#pragma unroll
    for (int n = 0; n < 4; ++n) {
      float s = ssc[n], c = ccc[n];
      s += __shfl_xor(s, 16, 64); c += __shfl_xor(c, 16, 64);
      s += __shfl_xor(s, 32, 64); c += __shfl_xor(c, 32, 64);
      if (g == 0) {
        partS[(size_t)gcolv[n] * NCH + chC] = s;
        partC[(size_t)gcolv[n] * NCH + chC] = c;
      }
    }
  }
}

// ---- kernel 3: per-row combine of 64 chunks -> rowLoss, rowCnt ----
__global__ void k_rowfin(const float* __restrict__ partS, const float* __restrict__ partC,
                         const float* __restrict__ pos, float* __restrict__ rowL,
                         float* __restrict__ rowC, int N) {
  int r = (blockIdx.x * blockDim.x + threadIdx.x) >> 6;
  int lane = threadIdx.x & 63;
  if (r >= N) return;
  float s = partS[(size_t)r * NCH + lane];
  float c = partC[(size_t)r * NCH + lane];
#pragma unroll
  for (int off = 32; off; off >>= 1) { s += __shfl_xor(s, off, 64); c += __shfl_xor(c, off, 64); }
  if (lane == 0) {
    rowL[r] = logf(s) - pos[r];
    rowC[r] = c;
  }
}

// ---- kernel 4: final reduction to (loss, avg_rank) ----
__global__ void k_final(const float* __restrict__ rowL, const float* __restrict__ rowC,
                        float* __restrict__ out, int N) {
  float ls = 0.f, cs = 0.f;
  for (int r = threadIdx.x; r < N; r += THREADS) { ls += rowL[r]; cs += rowC[r]; }
  __shared__ float l[THREADS], c[THREADS];
  l[threadIdx.x] = ls; c[threadIdx.x] = cs;
  __syncthreads();
  for (int off = THREADS / 2; off; off >>= 1) {
    if (threadIdx.x < off) { l[threadIdx.x] += l[threadIdx.x + off]; c[threadIdx.x] += c[threadIdx.x + off]; }
    __syncthreads();
  }
  if (threadIdx.x == 0) { out[0] = l[0] / (float)N; out[1] = c[0] / (float)N; }
}

extern "C" void kernel_launch(void* const* d_in, const int* in_sizes, int n_in,
                              void* d_out, int out_size, void* d_ws, size_t ws_size,
                              hipStream_t stream) {
  const float* zi = (const float*)d_in[0];
  const float* zj = (const float*)d_in[1];
  const float* temp = (const float*)d_in[2];
  float* out = (float*)d_out;

  const int B = in_sizes[0] / DDIM;   // 2048
  const int N = 2 * B;                // 4096

  unsigned short* znb = (unsigned short*)d_ws;          // N*DDIM bf16 = 4 MB
  float* fws = (float*)(znb + (size_t)N * DDIM);
  float* pos   = fws;                                    // N
  float* partS = pos + N;                                // N*NCH = 1 MB
  float* partC = partS + (size_t)N * NCH;                // N*NCH = 1 MB
  float* rowL  = partC + (size_t)N * NCH;                // N
  float* rowC  = rowL + N;                               // N

  k_prep<<<(B * 64) / THREADS, THREADS, 0, stream>>>(zi, zj, temp, znb, pos, B);
  const int ntiles = NT * (NT + 1) / 2;                  // 528 triangular tiles
  k_main<<<ntiles, THREADS, 0, stream>>>(znb, pos, temp, partS, partC, B);
  k_rowfin<<<(N * 64) / THREADS, THREADS, 0, stream>>>(partS, partC, pos, rowL, rowC, N);
  k_final<<<1, THREADS, 0, stream>>>(rowL, rowC, out, N);
}